// Round 18
// baseline (49.097 us; speedup 1.0000x reference)
//
#include <hip/hip_runtime.h>

// LNCC loss: I,J [16,1,768,768] f32 -> out [16] f32
// R18 = R17 (40.2us, 124 VGPR) with ALL out-loads replaced by register
// retention: CHUNK consumes its in-batch read-only, and the out-rows of
// chunk c are exactly W_c (c<=3) or I_{c-4} (c=4,5) — already in registers.
// Deletes 10 of 30 row-load-pairs per task (and their addressing VALU) at
// equal occupancy. Lifetime analysis: peak 6 live bufs (96 regs) + cs (20)
// + transients ~= 125 <= 128 cliff, which forces depth-1 in-prefetch
// (LD(I_{c+1}) issued at chunk c, ~700cy ahead; covers L2, most of HBM).
// Occupancy law honored: VGPR<=128 -> 4 waves/SIMD; 1024 blocks = 4/CU.

constexpr int BATCH = 16;
constexpr int H = 768;
constexpr int W = 768;
constexpr float INV_WS = 1.0f / 81.0f;
constexpr float EPS = 3.0590232050182579e-07f;   // exp(-15)

constexpr int SEG = 12;                   // output rows per wave task
constexpr int NSEG = H / SEG;             // 64
constexpr int BANDW = 248;                // output cols per band
constexpr int NTHREADS = 256;             // 4 waves = 4 bands of one (seg,b)

__global__ void zero_acc_kernel(float* acc) {
    if (threadIdx.x < BATCH) acc[threadIdx.x] = 0.0f;
}

#define F4ADD(a, u)    { a.x += u.x; a.y += u.y; a.z += u.z; a.w += u.w; }
#define F4SUB(a, u)    { a.x -= u.x; a.y -= u.y; a.z -= u.z; a.w -= u.w; }
#define F4FMA(a, u, v) { a.x = fmaf(u.x, v.x, a.x); a.y = fmaf(u.y, v.y, a.y); \
                         a.z = fmaf(u.z, v.z, a.z); a.w = fmaf(u.w, v.w, a.w); }
#define F4FMS(a, u, v) { a.x = fmaf(u.x, -v.x, a.x); a.y = fmaf(u.y, -v.y, a.y); \
                         a.z = fmaf(u.z, -v.z, a.z); a.w = fmaf(u.w, -v.w, a.w); }

// h[e] = sum of cs cols [c0+e, c0+e+8]; output col = c0+4+e = band*248+4*lane+e
#define HSUM_SHFL(c, h)                                                   \
    {                                                                     \
        const float s3 = c.w;                                             \
        const float s2 = c.w + c.z;                                       \
        const float s1 = s2 + c.y;                                        \
        const float s0 = s1 + c.x;          /* own total */               \
        const float p1 = c.x + c.y;                                       \
        const float p2 = p1 + c.z;                                        \
        const float pn = __shfl_down(s0, 1, 64);                          \
        const float q0 = __shfl_down(c.x, 2, 64);                         \
        const float q1 = __shfl_down(p1, 2, 64);                          \
        const float q2 = __shfl_down(p2, 2, 64);                          \
        const float q3 = __shfl_down(s0, 2, 64);                          \
        h[0] = s0 + pn + q0;                                              \
        h[1] = s1 + pn + q1;                                              \
        h[2] = s2 + pn + q2;                                              \
        h[3] = s3 + pn + q3;                                              \
    }

// load 2 rows (rbase, rbase+1) PRE-MASKED: addr clamped, value scaled by
// (row in [0,H) ? fm : 0); batches are read-only thereafter.
#define LD2(NI, NJ, rbase)                                                \
    {                                                                     \
        _Pragma("unroll")                                                 \
        for (int k = 0; k < 2; ++k) {                                     \
            const int rr = (rbase) + k;                                   \
            const int rc = min(max(rr, 0), H - 1);                        \
            const float mk = (rr >= 0 && rr < H) ? fm : 0.0f;             \
            float4 ti = *(const float4*)(Ib + (size_t)rc * W + ca);       \
            float4 tj = *(const float4*)(Jb + (size_t)rc * W + ca);       \
            ti.x *= mk; ti.y *= mk; ti.z *= mk; ti.w *= mk;               \
            tj.x *= mk; tj.y *= mk; tj.z *= mk; tj.w *= mk;               \
            NI[k] = ti; NJ[k] = tj;                                       \
        }                                                                 \
    }

// compute 2 output rows; reads (VI,VJ) as in-rows and (OI,OJ) as out-rows.
// Both batches are pre-masked raw rows; neither is modified.
#define CHUNK(VI, VJ, OI, OJ)                                             \
    _Pragma("unroll")                                                     \
    for (int k = 0; k < 2; ++k) {                                         \
        F4ADD(cs0, VI[k]) F4ADD(cs1, VJ[k])                               \
        F4FMA(cs2, VI[k], VI[k]) F4FMA(cs3, VJ[k], VJ[k])                 \
        F4FMA(cs4, VI[k], VJ[k])                                          \
        float hI[4], hJ[4], hII[4], hJJ[4], hIJ[4];                       \
        HSUM_SHFL(cs0, hI)                                                \
        HSUM_SHFL(cs1, hJ)                                                \
        HSUM_SHFL(cs2, hII)                                               \
        HSUM_SHFL(cs3, hJJ)                                               \
        HSUM_SHFL(cs4, hIJ)                                               \
        float rowsum = 0.0f;                                              \
        _Pragma("unroll")                                                 \
        for (int e = 0; e < 4; ++e) {                                     \
            const float u = -hI[e] * INV_WS;                              \
            const float cross = fmaf(u, hJ[e], hIJ[e]);                   \
            const float Ivar  = fmaf(u, hI[e], hII[e]);                   \
            const float Jvar  = fmaf(-hJ[e] * INV_WS, hJ[e], hJJ[e]);     \
            float prod = Ivar * Jvar;                                     \
            float num  = cross * cross;                                   \
            if (!(prod > EPS)) { prod = 1.0f; num = 1.0f; }               \
            float inv_;                                                   \
            asm("v_rcp_f32 %0, %1" : "=v"(inv_) : "v"(prod + EPS));       \
            rowsum = fmaf(num, inv_, rowsum);                             \
        }                                                                 \
        accum += live ? rowsum : 0.0f;                                    \
        F4SUB(cs0, OI[k]) F4SUB(cs1, OJ[k])                               \
        F4FMS(cs2, OI[k], OI[k]) F4FMS(cs3, OJ[k], OJ[k])                 \
        F4FMS(cs4, OI[k], OJ[k])                                          \
    }

__launch_bounds__(NTHREADS, 2)
__global__ void lncc_ret(const float* __restrict__ gI, const float* __restrict__ gJ,
                         float* __restrict__ acc)
{
    __shared__ float wsum[4];

    const int lane = threadIdx.x & 63;
    const int band = threadIdx.x >> 6;                   // 0..3
    const int r0   = blockIdx.x * SEG;
    const int b    = blockIdx.y;
    const int c0   = band * BANDW - 4 + 4 * lane;        // own cs base col
    const float fm = (c0 >= 0 && c0 + 3 < W) ? 1.0f : 0.0f;
    const int ca   = min(max(c0, 0), W - 4);             // 16B-aligned clamp
    const bool live = (lane <= 61) && (band * BANDW + 4 * lane + 3 < W);

    const float* __restrict__ Ib = gI + (size_t)b * (H * W);
    const float* __restrict__ Jb = gJ + (size_t)b * (H * W);

    float4 cs0 = {0,0,0,0}, cs1 = {0,0,0,0}, cs2 = {0,0,0,0},
           cs3 = {0,0,0,0}, cs4 = {0,0,0,0};

    // ---- warm-up chunks: rows r0-4..r0+3, retained as out-rows for c0..c3
    float4 W0i[2], W0j[2], W1i[2], W1j[2], W2i[2], W2j[2], W3i[2], W3j[2];
    LD2(W0i, W0j, r0 - 4)
    LD2(W1i, W1j, r0 - 2)
    LD2(W2i, W2j, r0)
    LD2(W3i, W3j, r0 + 2)

    // in-chunk 0 preload (rows r0+4,5); I0/I1 retained as out-rows for c4/c5
    float4 I0i[2], I0j[2], I1i[2], I1j[2], I2i[2], I2j[2];
    float4 I3i[2], I3j[2], I4i[2], I4j[2], I5i[2], I5j[2];
    LD2(I0i, I0j, r0 + 4)

    // ---- warm-up accumulate (~700 cy, covers preload latency) ----
#define WACC(WI, WJ)                                                      \
    _Pragma("unroll")                                                     \
    for (int k = 0; k < 2; ++k) {                                         \
        F4ADD(cs0, WI[k]) F4ADD(cs1, WJ[k])                               \
        F4FMA(cs2, WI[k], WI[k]) F4FMA(cs3, WJ[k], WJ[k])                 \
        F4FMA(cs4, WI[k], WJ[k])                                          \
    }
    WACC(W0i, W0j) WACC(W1i, W1j) WACC(W2i, W2j) WACC(W3i, W3j)
#undef WACC

    float accum = 0.0f;

    // ---- 6 chunks of 2 rows (SEG = 12); in-loads depth-1; NO out-loads ----
    LD2(I1i, I1j, r0 + 6)   CHUNK(I0i, I0j, W0i, W0j)   // rows r0,1
    LD2(I2i, I2j, r0 + 8)   CHUNK(I1i, I1j, W1i, W1j)   // rows r0+2,3
    LD2(I3i, I3j, r0 + 10)  CHUNK(I2i, I2j, W2i, W2j)   // rows r0+4,5
    LD2(I4i, I4j, r0 + 12)  CHUNK(I3i, I3j, W3i, W3j)   // rows r0+6,7
    LD2(I5i, I5j, r0 + 14)  CHUNK(I4i, I4j, I0i, I0j)   // rows r0+8,9
                            CHUNK(I5i, I5j, I1i, I1j)   // rows r0+10,11

    // ---- wave reduce -> block reduce -> one atomic per block ----
    #pragma unroll
    for (int off = 32; off > 0; off >>= 1)
        accum += __shfl_xor(accum, off, 64);
    if (lane == 0) wsum[band] = accum;
    __syncthreads();
    if (threadIdx.x == 0)
        atomicAdd(&acc[b], wsum[0] + wsum[1] + wsum[2] + wsum[3]);
}

__global__ void finalize_kernel(const float* __restrict__ acc, float* __restrict__ out) {
    if (threadIdx.x < BATCH)
        out[threadIdx.x] = 1.0f - acc[threadIdx.x] * (1.0f / (float)(H * W));
}

extern "C" void kernel_launch(void* const* d_in, const int* in_sizes, int n_in,
                              void* d_out, int out_size, void* d_ws, size_t ws_size,
                              hipStream_t stream) {
    const float* I = (const float*)d_in[0];
    const float* J = (const float*)d_in[1];
    float* out = (float*)d_out;
    float* acc = (float*)d_ws;

    zero_acc_kernel<<<1, 64, 0, stream>>>(acc);

    dim3 grid(NSEG, BATCH);   // 64 x 16 = 1024 blocks = 4/CU, 16 waves/CU
    lncc_ret<<<grid, NTHREADS, 0, stream>>>(I, J, acc);

    finalize_kernel<<<1, 64, 0, stream>>>(acc, out);
}